// Round 17
// baseline (500.850 us; speedup 1.0000x reference)
//
#include <hip/hip_runtime.h>
#include <hip/hip_bf16.h>
#include <cstdint>

#define B_ 16
#define N_ 2048
#define D_ 64

typedef __bf16 bf16x8_t __attribute__((ext_vector_type(8)));
typedef __bf16 bf16x4_t __attribute__((ext_vector_type(4)));
typedef float f32x4_t __attribute__((ext_vector_type(4)));
typedef int   int4_t  __attribute__((ext_vector_type(4)));

// LDS (75008 B -> 2 blocks/CU). KSTR=136 (rows 8B-aligned; frag reads via 2xb64).
// KH 0, KL 17408 (K single-buffered)
// V0 34816, V1 52224 (V double-buffered, pair-PV)
// M  69632 [32][132] single-buffered
// Lb 73856 (8w x 32 f32), Ri 74880 (32 f32)
#define KSTR 136
#define KHB  0
#define KLB  17408
#define V0B  34816
#define V1B  52224
#define MB_  69632
#define MSTR 132
#define LBB  73856
#define RIB  74880
#define LDSZ 75008

#define SBAR() do { asm volatile("s_waitcnt lgkmcnt(0)" ::: "memory");  \
                    __builtin_amdgcn_s_barrier();                        \
                    __builtin_amdgcn_sched_barrier(0); } while (0)

__device__ __forceinline__ void split8r(const f32x4_t a, const f32x4_t bq, bf16x8_t& h, bf16x8_t& lo) {
    #pragma unroll
    for (int j = 0; j < 4; ++j) {
        __bf16 h0 = (__bf16)a[j];
        h[j] = h0;     lo[j]     = (__bf16)(a[j]  - (float)h0);
        __bf16 h1 = (__bf16)bq[j];
        h[4 + j] = h1; lo[4 + j] = (__bf16)(bq[j] - (float)h1);
    }
}
__device__ __forceinline__ void split4r(const f32x4_t a, bf16x4_t& h, bf16x4_t& lo) {
    #pragma unroll
    for (int j = 0; j < 4; ++j) {
        __bf16 h0 = (__bf16)a[j];
        h[j] = h0;  lo[j] = (__bf16)(a[j] - (float)h0);
    }
}
__device__ __forceinline__ bf16x8_t lds_read8(const char* p) {   // 2 aligned b64 reads
    bf16x4_t a = *(const bf16x4_t*)(p);
    bf16x4_t b = *(const bf16x4_t*)(p + 8);
    return __builtin_shufflevector(a, b, 0, 1, 2, 3, 4, 5, 6, 7);
}

__global__ __launch_bounds__(512, 4)
void attn_fused(const float* __restrict__ qg,
                const float* __restrict__ kg,
                const float* __restrict__ vg,
                const int*   __restrict__ mg,
                float* __restrict__ out0,
                float* __restrict__ out1)
{
    __shared__ __align__(16) char lds[LDSZ];

    const int tid = threadIdx.x;
    const int w = tid >> 6, l = tid & 63, g = l >> 4, c = l & 15;

    // 1024 blocks; XCD-chunked bijective swizzle (1024 % 8 == 0)
    const int bid = ((int)blockIdx.x & 7) * 128 + ((int)blockIdx.x >> 3);
    const int b  = bid >> 6;
    const int m0 = (bid & 63) << 5;          // 32-row m-tile

    bf16x8_t q0h0, q0l0, q0h1, q0l1, q1h0, q1l0, q1h1, q1l1;
    {
        const float* qr0 = qg + ((size_t)(b * N_ + m0 + c)) * D_ + g * 8;
        split8r(*(const f32x4_t*)qr0, *(const f32x4_t*)(qr0 + 4), q0h0, q0l0);
        split8r(*(const f32x4_t*)(qr0 + 32), *(const f32x4_t*)(qr0 + 36), q0h1, q0l1);
        const float* qr1 = qr0 + 16 * D_;
        split8r(*(const f32x4_t*)qr1, *(const f32x4_t*)(qr1 + 4), q1h0, q1l0);
        split8r(*(const f32x4_t*)(qr1 + 32), *(const f32x4_t*)(qr1 + 36), q1h1, q1l1);
    }

    const int krow_ = tid >> 4;              // staging row, +32*u
    const int kcol_ = (tid & 15) * 4;        // float col
    const int mrow_ = tid >> 4;              // mask row 0..31
    const int mcol8 = (tid & 15) * 8;
    const int* mgrow = mg + (size_t)(b * N_ + m0 + mrow_) * N_ + mcol8;
    const int fragoff = (16 * w + c) * KSTR + g * 16;
    const int moff0 = c * MSTR + 16 * w + 4 * g;
    const int moff1 = (16 + c) * MSTR + 16 * w + 4 * g;

    // E-plane: block-private bf16 [32 m][2048 n] in back half of this tile's out1 region
    char* Eb = (char*)out1 + ((size_t)(b * N_ + m0)) * N_ * 4 + 131072;
    char* Ep0 = Eb + c * 4096 + (16 * w + 4 * g) * 2;          // + i*256 per half
    char* Ep1 = Eb + (16 + c) * 4096 + (16 * w + 4 * g) * 2;

    float lsum0 = 0.f, lsum1 = 0.f;
    f32x4_t of0[4] = {}, of1[4] = {};
    bf16x4_t peP0, peP1;                     // h0's pe, consumed by PV at h1

    f32x4_t kin[4], vin[4]; int4_t mA, mB;
    #pragma unroll
    for (int u = 0; u < 4; ++u) {
        const size_t roff = ((size_t)(b * N_ + krow_ + 32 * u)) * D_ + kcol_;
        kin[u] = *(const f32x4_t*)(kg + roff);
        vin[u] = *(const f32x4_t*)(vg + roff);
    }
    mA = *(const int4_t*)(mgrow);
    mB = *(const int4_t*)(mgrow + 4);

    #pragma unroll 1
    for (int p = 0; p < 8; ++p) {
        #pragma unroll
        for (int h = 0; h < 2; ++h) {
            const int i = 2 * p + h;
            char* VS = h ? (lds + V1B) : (lds + V0B);

            // ---- stage half i (K single-buf, V slot h, M single) ----
            #pragma unroll
            for (int u = 0; u < 4; ++u) {
                const int row = krow_ + 32 * u;
                bf16x4_t kh, klo;
                split4r(kin[u], kh, klo);
                *(bf16x4_t*)(lds + KHB + row * KSTR + kcol_ * 2) = kh;
                *(bf16x4_t*)(lds + KLB + row * KSTR + kcol_ * 2) = klo;
                bf16x4_t v4;
                #pragma unroll
                for (int j = 0; j < 4; ++j) v4[j] = (__bf16)vin[u][j];
                *(bf16x4_t*)(VS + row * KSTR + kcol_ * 2) = v4;
            }
            {
                unsigned mb0 = 0, mb1 = 0;
                #pragma unroll
                for (int j = 0; j < 4; ++j) {
                    mb0 |= (mA[j] ? 1u : 0u) << (8 * j);
                    mb1 |= (mB[j] ? 1u : 0u) << (8 * j);
                }
                *(unsigned*)(lds + MB_ + mrow_ * MSTR + mcol8)     = mb0;
                *(unsigned*)(lds + MB_ + mrow_ * MSTR + mcol8 + 4) = mb1;
            }

            // ---- prefetch half i+1 (in flight across both barriers) ----
            if (i < 15) {
                const int nnext = (i + 1) * 128;
                #pragma unroll
                for (int u = 0; u < 4; ++u) {
                    const size_t roff = ((size_t)(b * N_ + nnext + krow_ + 32 * u)) * D_ + kcol_;
                    kin[u] = *(const f32x4_t*)(kg + roff);
                    vin[u] = *(const f32x4_t*)(vg + roff);
                }
                mA = *(const int4_t*)(mgrow + nnext);
                mB = *(const int4_t*)(mgrow + nnext + 4);
            }
            SBAR();

            // ---- QK^T (swapped), 4 chains; mask+exp; E direct global store ----
            bf16x4_t pe0, pe1;
            {
                const char* ka = lds + KHB + fragoff;
                const char* la = lds + KLB + fragoff;
                bf16x8_t ka0 = lds_read8(ka);
                bf16x8_t ka1 = lds_read8(ka + 64);
                bf16x8_t la0 = lds_read8(la);
                bf16x8_t la1 = lds_read8(la + 64);
                f32x4_t z = {0.f, 0.f, 0.f, 0.f};
                __builtin_amdgcn_s_setprio(1);
                f32x4_t a0a = __builtin_amdgcn_mfma_f32_16x16x32_bf16(ka0, q0h0, z, 0, 0, 0);
                f32x4_t a0b = __builtin_amdgcn_mfma_f32_16x16x32_bf16(ka1, q0h1, z, 0, 0, 0);
                f32x4_t a1a = __builtin_amdgcn_mfma_f32_16x16x32_bf16(ka0, q1h0, z, 0, 0, 0);
                f32x4_t a1b = __builtin_amdgcn_mfma_f32_16x16x32_bf16(ka1, q1h1, z, 0, 0, 0);
                a0a = __builtin_amdgcn_mfma_f32_16x16x32_bf16(la0, q0h0, a0a, 0, 0, 0);
                a0b = __builtin_amdgcn_mfma_f32_16x16x32_bf16(la1, q0h1, a0b, 0, 0, 0);
                a1a = __builtin_amdgcn_mfma_f32_16x16x32_bf16(la0, q1h0, a1a, 0, 0, 0);
                a1b = __builtin_amdgcn_mfma_f32_16x16x32_bf16(la1, q1h1, a1b, 0, 0, 0);
                a0a = __builtin_amdgcn_mfma_f32_16x16x32_bf16(ka0, q0l0, a0a, 0, 0, 0);
                a0b = __builtin_amdgcn_mfma_f32_16x16x32_bf16(ka1, q0l1, a0b, 0, 0, 0);
                a1a = __builtin_amdgcn_mfma_f32_16x16x32_bf16(ka0, q1l0, a1a, 0, 0, 0);
                a1b = __builtin_amdgcn_mfma_f32_16x16x32_bf16(ka1, q1l1, a1b, 0, 0, 0);
                __builtin_amdgcn_s_setprio(0);
                f32x4_t a0 = a0a + a0b;
                f32x4_t a1 = a1a + a1b;
                const unsigned mu0 = *(const unsigned*)(lds + MB_ + moff0);
                const unsigned mu1 = *(const unsigned*)(lds + MB_ + moff1);
                #pragma unroll
                for (int r = 0; r < 4; ++r) {
                    float e0 = ((mu0 >> (8 * r)) & 255u) ? 0.f : __expf(a0[r]);
                    float e1 = ((mu1 >> (8 * r)) & 255u) ? 0.f : __expf(a1[r]);
                    lsum0 += e0; lsum1 += e1;
                    pe0[r] = (__bf16)e0; pe1[r] = (__bf16)e1;
                }
                *(bf16x4_t*)(Ep0 + i * 256) = pe0;     // unnormalized E, bf16
                *(bf16x4_t*)(Ep1 + i * 256) = pe1;
            }

            if (h == 0) {
                peP0 = pe0; peP1 = pe1;
            } else {
                // ---- PV per pair: A=[peP|pe], B = V0|V1 (verified x32 path) ----
                bf16x8_t pa80 = __builtin_shufflevector(peP0, pe0, 0, 1, 2, 3, 4, 5, 6, 7);
                bf16x8_t pa81 = __builtin_shufflevector(peP1, pe1, 0, 1, 2, 3, 4, 5, 6, 7);
                __builtin_amdgcn_s_setprio(1);
                #pragma unroll
                for (int t = 0; t < 4; ++t) {
                    bf16x8_t vbf;
                    #pragma unroll
                    for (int j = 0; j < 4; ++j) {
                        const int rr = 16 * w + 4 * g + j;
                        vbf[j]     = *(const __bf16*)(lds + V0B + rr * KSTR + (16 * t + c) * 2);
                        vbf[4 + j] = *(const __bf16*)(lds + V1B + rr * KSTR + (16 * t + c) * 2);
                    }
                    of0[t] = __builtin_amdgcn_mfma_f32_16x16x32_bf16(pa80, vbf, of0[t], 0, 0, 0);
                    of1[t] = __builtin_amdgcn_mfma_f32_16x16x32_bf16(pa81, vbf, of1[t], 0, 0, 0);
                }
                __builtin_amdgcn_s_setprio(0);
            }
            SBAR();    // protects K/M (and V slots) before next stage
        }
    }

    // =============== epilogue ===============
    asm volatile("s_waitcnt vmcnt(0)" ::: "memory");   // all E-plane stores done
    __syncthreads();

    lsum0 += __shfl_xor(lsum0, 16); lsum0 += __shfl_xor(lsum0, 32);
    lsum1 += __shfl_xor(lsum1, 16); lsum1 += __shfl_xor(lsum1, 32);
    float* Lbuf = (float*)(lds + LBB);
    if (l < 16) {
        Lbuf[w * 32 + l]      = lsum0;
        Lbuf[w * 32 + 16 + l] = lsum1;
    }
    // O partials, m-tile 0, into dead K region
    {
        float* Ow = (float*)(lds + w * 4096);
        #pragma unroll
        for (int t = 0; t < 4; ++t)
            #pragma unroll
            for (int r = 0; r < 4; ++r)
                Ow[(g * 4 + r) * 64 + t * 16 + c] = of0[t][r];
    }
    __syncthreads();

    float* Rinv = (float*)(lds + RIB);
    if (tid < 32) {
        float s = 0.f;
        #pragma unroll
        for (int ww = 0; ww < 8; ++ww) s += Lbuf[ww * 32 + tid];
        Rinv[tid] = 1.0f / s;
    }
    __syncthreads();

    if (tid < 256) {
        const int row = tid >> 4;
        const int dc  = (tid & 15) * 4;
        const float ri = Rinv[row];
        f32x4_t o = {0.f, 0.f, 0.f, 0.f};
        #pragma unroll
        for (int ww = 0; ww < 8; ++ww)
            o += *(const f32x4_t*)((const float*)(lds + ww * 4096) + row * 64 + dc);
        o.x *= ri; o.y *= ri; o.z *= ri; o.w *= ri;
        *(f32x4_t*)(out0 + ((size_t)(b * N_ + m0 + row)) * D_ + dc) = o;
    }
    __syncthreads();

    // O partials, m-tile 1
    {
        float* Ow = (float*)(lds + w * 4096);
        #pragma unroll
        for (int t = 0; t < 4; ++t)
            #pragma unroll
            for (int r = 0; r < 4; ++r)
                Ow[(g * 4 + r) * 64 + t * 16 + c] = of1[t][r];
    }
    __syncthreads();

    if (tid < 256) {
        const int row = tid >> 4;
        const int dc  = (tid & 15) * 4;
        const float ri = Rinv[16 + row];
        f32x4_t o = {0.f, 0.f, 0.f, 0.f};
        #pragma unroll
        for (int ww = 0; ww < 8; ++ww)
            o += *(const f32x4_t*)((const float*)(lds + ww * 4096) + row * 64 + dc);
        o.x *= ri; o.y *= ri; o.z *= ri; o.w *= ri;
        *(f32x4_t*)(out0 + ((size_t)(b * N_ + m0 + 16 + row)) * D_ + dc) = o;
    }

    // ---- out1: read E-plane (dense, L2-hot), normalize, write fp32 (dense) ----
    {
        const int r  = tid >> 4;             // 0..31
        const int ch = tid & 15;
        const float ri = Rinv[r];
        const char* esrc = Eb + r * 4096 + ch * 16;
        bf16x8_t e[16];
        #pragma unroll
        for (int k = 0; k < 16; ++k) e[k] = *(const bf16x8_t*)(esrc + k * 256);
        __syncthreads();                     // all E reads complete before overwrites
        float* dst = out1 + (size_t)(b * N_ + m0 + r) * N_ + ch * 8;
        #pragma unroll
        for (int k = 0; k < 16; ++k) {
            f32x4_t o0, o1;
            #pragma unroll
            for (int j = 0; j < 4; ++j) {
                o0[j] = (float)e[k][j]     * ri;
                o1[j] = (float)e[k][4 + j] * ri;
            }
            *(f32x4_t*)(dst + k * 128)     = o0;
            *(f32x4_t*)(dst + k * 128 + 4) = o1;
        }
    }
}

extern "C" void kernel_launch(void* const* d_in, const int* in_sizes, int n_in,
                              void* d_out, int out_size, void* d_ws, size_t ws_size,
                              hipStream_t stream) {
    (void)in_sizes; (void)n_in; (void)out_size; (void)d_ws; (void)ws_size;
    const float* q = (const float*)d_in[0];
    const float* k = (const float*)d_in[1];
    const float* v = (const float*)d_in[2];
    const int* mask = (const int*)d_in[3];
    float* out0 = (float*)d_out;                          // [B,N,D]
    float* out1 = out0 + (size_t)B_ * N_ * D_;            // [B,N,N]
    attn_fused<<<dim3(B_ * (N_ / 32)), dim3(512), 0, stream>>>(q, k, v, mask, out0, out1);
}

// Round 18
// 177.519 us; speedup vs baseline: 2.8214x; 2.8214x over previous
//
#include <hip/hip_runtime.h>
#include <hip/hip_bf16.h>
#include <cstdint>

#define B_ 16
#define N_ 2048
#define D_ 64

typedef __bf16 bf16x8_t __attribute__((ext_vector_type(8)));
typedef __bf16 bf16x4_t __attribute__((ext_vector_type(4)));
typedef float f32x4_t __attribute__((ext_vector_type(4)));
typedef int   int4_t  __attribute__((ext_vector_type(4)));

// LDS map (157KB; 1 block/CU — register-bound there anyway).
// K double-buffered: buf b at b*36864 (hi +0, lo +18432), rows [128][KSTR=144B]
// V 4 slots:        slot s at 73728 + s*18432
// M double-buffered: buf b at 147456 + b*4224, [32 m][132 B]
// Lbuf 155904 (8w x 32 f32), Rinv 156928 (32 f32)
#define KSTR 144
#define VBASE 73728
#define MBASE 147456
#define MSTR 132
#define LBB  155904
#define RIB  156928
#define LDSZ 157056

// barrier WITHOUT vmcnt drain; rule #18 fence after.
#define SBAR() do { asm volatile("s_waitcnt lgkmcnt(0)" ::: "memory");  \
                    __builtin_amdgcn_s_barrier();                        \
                    __builtin_amdgcn_sched_barrier(0); } while (0)

__device__ __forceinline__ void split8r(const f32x4_t a, const f32x4_t bq, bf16x8_t& h, bf16x8_t& lo) {
    #pragma unroll
    for (int j = 0; j < 4; ++j) {
        __bf16 h0 = (__bf16)a[j];
        h[j] = h0;     lo[j]     = (__bf16)(a[j]  - (float)h0);
        __bf16 h1 = (__bf16)bq[j];
        h[4 + j] = h1; lo[4 + j] = (__bf16)(bq[j] - (float)h1);
    }
}
__device__ __forceinline__ void split4r(const f32x4_t a, bf16x4_t& h, bf16x4_t& lo) {
    #pragma unroll
    for (int j = 0; j < 4; ++j) {
        __bf16 h0 = (__bf16)a[j];
        h[j] = h0;  lo[j] = (__bf16)(a[j] - (float)h0);
    }
}

__global__ __launch_bounds__(512, 2)
void attn_fused(const float* __restrict__ qg,
                const float* __restrict__ kg,
                const float* __restrict__ vg,
                const int*   __restrict__ mg,
                float* __restrict__ out0,
                float* __restrict__ out1)
{
    __shared__ __align__(16) char lds[LDSZ];

    const int tid = threadIdx.x;
    const int w = tid >> 6, l = tid & 63, g = l >> 4, c = l & 15;

    // 1024 blocks; XCD-chunked bijective swizzle (1024 % 8 == 0)
    const int bid = ((int)blockIdx.x & 7) * 128 + ((int)blockIdx.x >> 3);
    const int b  = bid >> 6;
    const int m0 = (bid & 63) << 5;          // 32-row m-tile

    // Q fragments for both 16-row q-tiles
    bf16x8_t q0h0, q0l0, q0h1, q0l1, q1h0, q1l0, q1h1, q1l1;
    {
        const float* qr0 = qg + ((size_t)(b * N_ + m0 + c)) * D_ + g * 8;
        split8r(*(const f32x4_t*)qr0, *(const f32x4_t*)(qr0 + 4), q0h0, q0l0);
        split8r(*(const f32x4_t*)(qr0 + 32), *(const f32x4_t*)(qr0 + 36), q0h1, q0l1);
        const float* qr1 = qr0 + 16 * D_;
        split8r(*(const f32x4_t*)qr1, *(const f32x4_t*)(qr1 + 4), q1h0, q1l0);
        split8r(*(const f32x4_t*)(qr1 + 32), *(const f32x4_t*)(qr1 + 36), q1h1, q1l1);
    }

    const int krow_ = tid >> 4;              // staging row, +32*u
    const int kcol_ = (tid & 15) * 4;        // float col
    const int mrow_ = tid >> 4;              // mask row 0..31
    const int mcol8 = (tid & 15) * 8;        // 8 int cols / thread
    const int* mgrow = mg + (size_t)(b * N_ + m0 + mrow_) * N_ + mcol8;

    float lsum0 = 0.f, lsum1 = 0.f;
    f32x4_t of0[4] = {}, of1[4] = {};
    bf16x4_t paE0[16], paE1[16];             // statically indexed (full unroll)

    f32x4_t kin[4], vin[4]; int4_t mA, mB;
    #pragma unroll
    for (int u = 0; u < 4; ++u) {
        const size_t roff = ((size_t)(b * N_ + krow_ + 32 * u)) * D_ + kcol_;
        kin[u] = *(const f32x4_t*)(kg + roff);
        vin[u] = *(const f32x4_t*)(vg + roff);
    }
    mA = *(const int4_t*)(mgrow);
    mB = *(const int4_t*)(mgrow + 4);

    #pragma unroll
    for (int i = 0; i < 16; ++i) {
        const int buf = i & 1;
        const int vs  = i & 3;
        char* KH = lds + buf * 36864;
        char* KL = KH + 18432;
        char* VS = lds + VBASE + vs * 18432;
        char* MT = lds + MBASE + buf * 4224;

        // ---- 1. stage half i from prefetched regs ----
        #pragma unroll
        for (int u = 0; u < 4; ++u) {
            const int row = krow_ + 32 * u;
            bf16x4_t kh, klo;
            split4r(kin[u], kh, klo);
            *(bf16x4_t*)(KH + row * KSTR + kcol_ * 2) = kh;
            *(bf16x4_t*)(KL + row * KSTR + kcol_ * 2) = klo;
            bf16x4_t v4;
            #pragma unroll
            for (int j = 0; j < 4; ++j) v4[j] = (__bf16)vin[u][j];
            *(bf16x4_t*)(VS + row * KSTR + kcol_ * 2) = v4;
        }
        {
            unsigned mb0 = 0, mb1 = 0;
            #pragma unroll
            for (int j = 0; j < 4; ++j) {
                mb0 |= (mA[j] ? 1u : 0u) << (8 * j);
                mb1 |= (mB[j] ? 1u : 0u) << (8 * j);
            }
            *(unsigned*)(MT + mrow_ * MSTR + mcol8)     = mb0;
            *(unsigned*)(MT + mrow_ * MSTR + mcol8 + 4) = mb1;
        }

        // ---- 2. issue loads for half i+1 (in flight across barrier + compute) ----
        if (i < 15) {
            const int nnext = (i + 1) * 128;
            #pragma unroll
            for (int u = 0; u < 4; ++u) {
                const size_t roff = ((size_t)(b * N_ + nnext + krow_ + 32 * u)) * D_ + kcol_;
                kin[u] = *(const f32x4_t*)(kg + roff);
                vin[u] = *(const f32x4_t*)(vg + roff);
            }
            mA = *(const int4_t*)(mgrow + nnext);
            mB = *(const int4_t*)(mgrow + nnext + 4);
        }
        SBAR();                               // the ONLY barrier this half

        // ---- 3. deferred PV for pair (i-2)/2 (V slots (i-2)&3, (i-1)&3) ----
        if ((i >= 2) && ((i & 1) == 0)) {
            const int pp = (i - 2) / 2;
            const char* VA  = lds + VBASE + ((i - 2) & 3) * 18432;
            const char* VBs = lds + VBASE + ((i - 1) & 3) * 18432;
            bf16x8_t pa80 = __builtin_shufflevector(paE0[2 * pp], paE0[2 * pp + 1],
                                                    0, 1, 2, 3, 4, 5, 6, 7);
            bf16x8_t pa81 = __builtin_shufflevector(paE1[2 * pp], paE1[2 * pp + 1],
                                                    0, 1, 2, 3, 4, 5, 6, 7);
            __builtin_amdgcn_s_setprio(1);
            #pragma unroll
            for (int t = 0; t < 4; ++t) {
                bf16x8_t vbf;
                #pragma unroll
                for (int j = 0; j < 4; ++j) {
                    const int rr = 16 * w + 4 * g + j;
                    vbf[j]     = *(const __bf16*)(VA  + rr * KSTR + (16 * t + c) * 2);
                    vbf[4 + j] = *(const __bf16*)(VBs + rr * KSTR + (16 * t + c) * 2);
                }
                of0[t] = __builtin_amdgcn_mfma_f32_16x16x32_bf16(pa80, vbf, of0[t], 0, 0, 0);
                of1[t] = __builtin_amdgcn_mfma_f32_16x16x32_bf16(pa81, vbf, of1[t], 0, 0, 0);
            }
            __builtin_amdgcn_s_setprio(0);
        }

        // ---- 4. QK^T (swapped), 4 independent accumulator chains ----
        {
            const char* ka = KH + (16 * w + c) * KSTR + g * 16;
            const char* la = KL + (16 * w + c) * KSTR + g * 16;
            bf16x8_t ka0 = *(const bf16x8_t*)(ka);
            bf16x8_t ka1 = *(const bf16x8_t*)(ka + 64);
            bf16x8_t la0 = *(const bf16x8_t*)(la);
            bf16x8_t la1 = *(const bf16x8_t*)(la + 64);
            f32x4_t z = {0.f, 0.f, 0.f, 0.f};
            __builtin_amdgcn_s_setprio(1);
            f32x4_t a0a = __builtin_amdgcn_mfma_f32_16x16x32_bf16(ka0, q0h0, z, 0, 0, 0);
            f32x4_t a0b = __builtin_amdgcn_mfma_f32_16x16x32_bf16(ka1, q0h1, z, 0, 0, 0);
            f32x4_t a1a = __builtin_amdgcn_mfma_f32_16x16x32_bf16(ka0, q1h0, z, 0, 0, 0);
            f32x4_t a1b = __builtin_amdgcn_mfma_f32_16x16x32_bf16(ka1, q1h1, z, 0, 0, 0);
            a0a = __builtin_amdgcn_mfma_f32_16x16x32_bf16(la0, q0h0, a0a, 0, 0, 0);
            a0b = __builtin_amdgcn_mfma_f32_16x16x32_bf16(la1, q0h1, a0b, 0, 0, 0);
            a1a = __builtin_amdgcn_mfma_f32_16x16x32_bf16(la0, q1h0, a1a, 0, 0, 0);
            a1b = __builtin_amdgcn_mfma_f32_16x16x32_bf16(la1, q1h1, a1b, 0, 0, 0);
            a0a = __builtin_amdgcn_mfma_f32_16x16x32_bf16(ka0, q0l0, a0a, 0, 0, 0);
            a0b = __builtin_amdgcn_mfma_f32_16x16x32_bf16(ka1, q0l1, a0b, 0, 0, 0);
            a1a = __builtin_amdgcn_mfma_f32_16x16x32_bf16(ka0, q1l0, a1a, 0, 0, 0);
            a1b = __builtin_amdgcn_mfma_f32_16x16x32_bf16(ka1, q1l1, a1b, 0, 0, 0);
            __builtin_amdgcn_s_setprio(0);
            f32x4_t a0 = a0a + a0b;
            f32x4_t a1 = a1a + a1b;
            const unsigned mu0 = *(const unsigned*)(MT + c * MSTR + 16 * w + 4 * g);
            const unsigned mu1 = *(const unsigned*)(MT + (16 + c) * MSTR + 16 * w + 4 * g);
            bf16x4_t pe0, pe1;
            #pragma unroll
            for (int r = 0; r < 4; ++r) {
                float e0 = ((mu0 >> (8 * r)) & 255u) ? 0.f : __expf(a0[r]);
                float e1 = ((mu1 >> (8 * r)) & 255u) ? 0.f : __expf(a1[r]);
                lsum0 += e0; lsum1 += e1;
                pe0[r] = (__bf16)e0; pe1[r] = (__bf16)e1;
            }
            paE0[i] = pe0;
            paE1[i] = pe1;
        }
    }

    // ---- tail PV: pair 7, V slots 2,3 ----
    {
        const char* VA  = lds + VBASE + 2 * 18432;
        const char* VBs = lds + VBASE + 3 * 18432;
        bf16x8_t pa80 = __builtin_shufflevector(paE0[14], paE0[15], 0, 1, 2, 3, 4, 5, 6, 7);
        bf16x8_t pa81 = __builtin_shufflevector(paE1[14], paE1[15], 0, 1, 2, 3, 4, 5, 6, 7);
        #pragma unroll
        for (int t = 0; t < 4; ++t) {
            bf16x8_t vbf;
            #pragma unroll
            for (int j = 0; j < 4; ++j) {
                const int rr = 16 * w + 4 * g + j;
                vbf[j]     = *(const __bf16*)(VA  + rr * KSTR + (16 * t + c) * 2);
                vbf[4 + j] = *(const __bf16*)(VBs + rr * KSTR + (16 * t + c) * 2);
            }
            of0[t] = __builtin_amdgcn_mfma_f32_16x16x32_bf16(pa80, vbf, of0[t], 0, 0, 0);
            of1[t] = __builtin_amdgcn_mfma_f32_16x16x32_bf16(pa81, vbf, of1[t], 0, 0, 0);
        }
    }

    // =============== epilogue (R12-verified) ===============
    lsum0 += __shfl_xor(lsum0, 16); lsum0 += __shfl_xor(lsum0, 32);
    lsum1 += __shfl_xor(lsum1, 16); lsum1 += __shfl_xor(lsum1, 32);
    float* Lbuf = (float*)(lds + LBB);
    if (l < 16) {
        Lbuf[w * 32 + l]      = lsum0;
        Lbuf[w * 32 + 16 + l] = lsum1;
    }

    // O partials, m-tile 0, into dead K region
    {
        float* Ow = (float*)(lds + w * 4096);
        #pragma unroll
        for (int t = 0; t < 4; ++t)
            #pragma unroll
            for (int r = 0; r < 4; ++r)
                Ow[(g * 4 + r) * 64 + t * 16 + c] = of0[t][r];
    }
    __syncthreads();

    float* Rinv = (float*)(lds + RIB);
    if (tid < 32) {
        float s = 0.f;
        #pragma unroll
        for (int ww = 0; ww < 8; ++ww) s += Lbuf[ww * 32 + tid];
        Rinv[tid] = 1.0f / s;
    }
    __syncthreads();

    if (tid < 256) {
        const int row = tid >> 4;
        const int dc  = (tid & 15) * 4;
        const float ri = Rinv[row];
        f32x4_t o = {0.f, 0.f, 0.f, 0.f};
        #pragma unroll
        for (int ww = 0; ww < 8; ++ww)
            o += *(const f32x4_t*)((const float*)(lds + ww * 4096) + row * 64 + dc);
        o.x *= ri; o.y *= ri; o.z *= ri; o.w *= ri;
        *(f32x4_t*)(out0 + ((size_t)(b * N_ + m0 + row)) * D_ + dc) = o;
    }
    __syncthreads();

    // O partials, m-tile 1 (reuse region)
    {
        float* Ow = (float*)(lds + w * 4096);
        #pragma unroll
        for (int t = 0; t < 4; ++t)
            #pragma unroll
            for (int r = 0; r < 4; ++r)
                Ow[(g * 4 + r) * 64 + t * 16 + c] = of1[t][r];
    }
    __syncthreads();

    if (tid < 256) {
        const int row = tid >> 4;
        const int dc  = (tid & 15) * 4;
        const float ri = Rinv[16 + row];
        f32x4_t o = {0.f, 0.f, 0.f, 0.f};
        #pragma unroll
        for (int ww = 0; ww < 8; ++ww)
            o += *(const f32x4_t*)((const float*)(lds + ww * 4096) + row * 64 + dc);
        o.x *= ri; o.y *= ri; o.z *= ri; o.w *= ri;
        *(f32x4_t*)(out0 + ((size_t)(b * N_ + m0 + 16 + row)) * D_ + dc) = o;
    }

    // out1: per-wave transpose bounce, 4 independent Et buffers per wave
    // (tile0/tile1 split + double-buffer across u) — breaks the serial
    // write->read->reuse chain of the single-buffer version.
    {
        char* EtW = lds + VBASE + w * 2560;              // 4 x 640B, wave-private (V dead)
        const int   rm  = l >> 2;
        const int   kq  = l & 3;
        const float ri0 = Rinv[rm];
        const float ri1 = Rinv[16 + rm];
        float* o1r0 = out1 + (size_t)(b * N_ + m0 + rm) * N_;
        float* o1r1 = out1 + (size_t)(b * N_ + m0 + 16 + rm) * N_;
        #pragma unroll
        for (int u = 0; u < 16; ++u) {
            char* Et0 = EtW + (u & 1) * 1280;            // tile0 buffer
            char* Et1 = Et0 + 640;                       // tile1 buffer
            const int n0 = u * 128 + 16 * w;
            *(bf16x4_t*)(Et0 + c * 40 + g * 8) = paE0[u];
            *(bf16x4_t*)(Et1 + c * 40 + g * 8) = paE1[u];
            bf16x4_t er0 = *(const bf16x4_t*)(Et0 + rm * 40 + kq * 8);
            bf16x4_t er1 = *(const bf16x4_t*)(Et1 + rm * 40 + kq * 8);
            f32x4_t o40, o41;
            #pragma unroll
            for (int j = 0; j < 4; ++j) {
                o40[j] = (float)er0[j] * ri0;
                o41[j] = (float)er1[j] * ri1;
            }
            *(f32x4_t*)(o1r0 + n0 + kq * 4) = o40;
            *(f32x4_t*)(o1r1 + n0 + kq * 4) = o41;
        }
    }
}

extern "C" void kernel_launch(void* const* d_in, const int* in_sizes, int n_in,
                              void* d_out, int out_size, void* d_ws, size_t ws_size,
                              hipStream_t stream) {
    (void)in_sizes; (void)n_in; (void)out_size; (void)d_ws; (void)ws_size;
    const float* q = (const float*)d_in[0];
    const float* k = (const float*)d_in[1];
    const float* v = (const float*)d_in[2];
    const int* mask = (const int*)d_in[3];
    float* out0 = (float*)d_out;                          // [B,N,D]
    float* out1 = out0 + (size_t)B_ * N_ * D_;            // [B,N,N]
    attn_fused<<<dim3(B_ * (N_ / 32)), dim3(512), 0, stream>>>(q, k, v, mask, out0, out1);
}